// Round 1
// baseline (1255.273 us; speedup 1.0000x reference)
//
#include <hip/hip_runtime.h>

#define EPSV 1e-8f
#define BN_EPS 1e-5f
#define LN_2PI 1.8378770664093453f

__device__ __forceinline__ float sigmoidf_(float x) { return 1.0f / (1.0f + expf(-x)); }

// ---------------- conv_a: 256->16, 3x3 pad1, BN + sigmoid ----------------
__global__ __launch_bounds__(256) void k_conv_a(
    const float* __restrict__ x, const float* __restrict__ w,
    const float* __restrict__ g, const float* __restrict__ b_,
    const float* __restrict__ m, const float* __restrict__ v,
    float* __restrict__ out)
{
    __shared__ float xs[128 * 64];
    const int t = threadIdx.x;
    const int bidx = blockIdx.x;
    const int pix = t & 63, py = pix >> 3, px = pix & 7;
    const int ocb = t >> 6;  // 0..3
    float acc[4] = {0.f, 0.f, 0.f, 0.f};
    for (int ch = 0; ch < 2; ++ch) {
        __syncthreads();
        for (int i = t; i < 128 * 64; i += 256)
            xs[i] = x[bidx * 16384 + ch * 8192 + i];
        __syncthreads();
        for (int icl = 0; icl < 128; ++icl) {
            int ic = ch * 128 + icl;
            #pragma unroll
            for (int ky = 0; ky < 3; ++ky) {
                int iy = py + ky - 1;
                #pragma unroll
                for (int kx = 0; kx < 3; ++kx) {
                    int ix = px + kx - 1;
                    float xv = (iy >= 0 && iy < 8 && ix >= 0 && ix < 8) ? xs[icl * 64 + iy * 8 + ix] : 0.f;
                    #pragma unroll
                    for (int q = 0; q < 4; ++q) {
                        int oc = ocb + 4 * q;
                        acc[q] = fmaf(w[(oc * 256 + ic) * 9 + ky * 3 + kx], xv, acc[q]);
                    }
                }
            }
        }
    }
    #pragma unroll
    for (int q = 0; q < 4; ++q) {
        int oc = ocb + 4 * q;
        float sc = g[oc] * rsqrtf(v[oc] + BN_EPS);
        float y = (acc[q] - m[oc]) * sc + b_[oc];
        out[(bidx * 16 + oc) * 64 + pix] = sigmoidf_(y);
    }
}

// ---------------- conv_pose: 256->256, 3x3 pad1, BN ----------------
__global__ __launch_bounds__(256) void k_conv_pose(
    const float* __restrict__ x, const float* __restrict__ w,
    const float* __restrict__ g, const float* __restrict__ b_,
    const float* __restrict__ m, const float* __restrict__ v,
    float* __restrict__ out)
{
    __shared__ float xs[128 * 64];
    const int t = threadIdx.x;
    const int bidx = blockIdx.x >> 4;
    const int ocg = blockIdx.x & 15;
    const int pix = t & 63, py = pix >> 3, px = pix & 7;
    const int ocb = t >> 6;
    float acc[4] = {0.f, 0.f, 0.f, 0.f};
    for (int ch = 0; ch < 2; ++ch) {
        __syncthreads();
        for (int i = t; i < 128 * 64; i += 256)
            xs[i] = x[bidx * 16384 + ch * 8192 + i];
        __syncthreads();
        for (int icl = 0; icl < 128; ++icl) {
            int ic = ch * 128 + icl;
            #pragma unroll
            for (int ky = 0; ky < 3; ++ky) {
                int iy = py + ky - 1;
                #pragma unroll
                for (int kx = 0; kx < 3; ++kx) {
                    int ix = px + kx - 1;
                    float xv = (iy >= 0 && iy < 8 && ix >= 0 && ix < 8) ? xs[icl * 64 + iy * 8 + ix] : 0.f;
                    #pragma unroll
                    for (int q = 0; q < 4; ++q) {
                        int oc = ocg * 16 + ocb + 4 * q;
                        acc[q] = fmaf(w[(oc * 256 + ic) * 9 + ky * 3 + kx], xv, acc[q]);
                    }
                }
            }
        }
    }
    #pragma unroll
    for (int q = 0; q < 4; ++q) {
        int oc = ocg * 16 + ocb + 4 * q;
        float sc = g[oc] * rsqrtf(v[oc] + BN_EPS);
        out[(bidx * 256 + oc) * 64 + pix] = (acc[q] - m[oc]) * sc + b_[oc];
    }
}

// ---------------- EM routing, conv-type (k=3, pad=1), A=B=16, P=16 ----------------
// grid: 32*64 blocks (b,l); block: 256 threads, thread = (o = t>>4, g = t&15)
// thread holds votes v[jj][p] for k = jj*16+g (kk_idx = jj, a_idx = g), its o.
__global__ __launch_bounds__(256, 2) void k_em_conv(
    const float* __restrict__ a_in, const float* __restrict__ pose_in,
    const float* __restrict__ W, const float* __restrict__ bu, const float* __restrict__ ba,
    const float* __restrict__ bng, const float* __restrict__ bnb,
    const float* __restrict__ bnm, const float* __restrict__ bnv,
    float* __restrict__ a_out_g, float* __restrict__ pose_out)
{
    __shared__ float pcT[16 * 144];       // transposed pose patches [p][k]
    __shared__ float ain[144];
    __shared__ float r_s[144 * 16];       // routing r[k][o] (reused for ln_p)
    __shared__ float rw_s[144 * 16];      // normalized r*a
    __shared__ float red[16 * 16 * 17];   // reduction scratch [o][g][p], padded
    __shared__ float mu16[256], sig16[256], lsig16[256];
    __shared__ float ps[256];
    __shared__ float rs[16], aout[16], laout[16];

    const int t = threadIdx.x;
    const int bidx = blockIdx.x >> 6;
    const int l = blockIdx.x & 63;
    const int y = l >> 3, xo = l & 7;
    const int o = t >> 4, g = t & 15;

    // ---- stage pose patches (transposed) + a patches; init r ----
    for (int idx = t; idx < 2304; idx += 256) {
        int p = idx / 144, k = idx - p * 144;
        int a = k & 15, kk = k >> 4;
        int iy = y + kk / 3 - 1, ix = xo + (kk % 3) - 1;
        float val = 0.f;
        if (iy >= 0 && iy < 8 && ix >= 0 && ix < 8)
            val = pose_in[(bidx * 256 + a * 16 + p) * 64 + iy * 8 + ix];
        pcT[p * 144 + k] = val;
        r_s[idx] = 1.0f / 16.0f;
    }
    if (t < 144) {
        int a = t & 15, kk = t >> 4;
        int iy = y + kk / 3 - 1, ix = xo + (kk % 3) - 1;
        ain[t] = (iy >= 0 && iy < 8 && ix >= 0 && ix < 8) ? a_in[(bidx * 16 + a) * 64 + iy * 8 + ix] : 0.f;
    }
    __syncthreads();

    // ---- votes (registers): v = pc @ W per (k,o) ----
    float v[9][16];
    const float4* W4 = reinterpret_cast<const float4*>(W);
    #pragma unroll
    for (int jj = 0; jj < 9; ++jj) {
        int k = jj * 16 + g;
        float pcl[16];
        #pragma unroll
        for (int p = 0; p < 16; ++p) pcl[p] = pcT[p * 144 + k];
        float wk[16];
        #pragma unroll
        for (int c = 0; c < 4; ++c) {
            float4 w4 = W4[(k * 16 + o) * 4 + c];
            wk[c * 4 + 0] = w4.x; wk[c * 4 + 1] = w4.y; wk[c * 4 + 2] = w4.z; wk[c * 4 + 3] = w4.w;
        }
        #pragma unroll
        for (int i = 0; i < 4; ++i)
            #pragma unroll
            for (int j = 0; j < 4; ++j) {
                float s = 0.f;
                #pragma unroll
                for (int h = 0; h < 4; ++h) s = fmaf(pcl[i * 4 + h], wk[h * 4 + j], s);
                v[jj][i * 4 + j] = s;
            }
    }

    float ml[16];
    for (int it = 0; it < 3; ++it) {
        float lam = (it == 0) ? 5.0e-4f : ((it == 1) ? 9.75e-4f : 1.42625e-3f);
        __syncthreads();
        // ---- M: rw = r*a normalized over o per k ----
        if (t < 144) {
            float tmp[16]; float den = EPSV;
            float av = ain[t];
            #pragma unroll
            for (int oo = 0; oo < 16; ++oo) { tmp[oo] = r_s[t * 16 + oo] * av; den += tmp[oo]; }
            float inv = 1.f / den;
            #pragma unroll
            for (int oo = 0; oo < 16; ++oo) rw_s[t * 16 + oo] = tmp[oo] * inv;
        }
        __syncthreads();
        // ---- r_sum over k ----
        {
            float s = 0.f;
            #pragma unroll
            for (int jj = 0; jj < 9; ++jj) s += rw_s[(jj * 16 + g) * 16 + o];
            ps[o * 16 + g] = s;
        }
        __syncthreads();
        if (t < 16) {
            float s = 0.f;
            #pragma unroll
            for (int gg = 0; gg < 16; ++gg) s += ps[t * 16 + gg];
            rs[t] = s;
        }
        __syncthreads();
        // ---- mu ----
        {
            float invr = 1.f / (rs[o] + EPSV);
            float pm[16];
            #pragma unroll
            for (int p = 0; p < 16; ++p) pm[p] = 0.f;
            #pragma unroll
            for (int jj = 0; jj < 9; ++jj) {
                float c = rw_s[(jj * 16 + g) * 16 + o] * invr;
                #pragma unroll
                for (int p = 0; p < 16; ++p) pm[p] = fmaf(c, v[jj][p], pm[p]);
            }
            #pragma unroll
            for (int p = 0; p < 16; ++p) red[(o * 16 + g) * 17 + p] = pm[p];
        }
        __syncthreads();
        {
            int oo = t >> 4, p = t & 15; float s = 0.f;
            #pragma unroll
            for (int gg = 0; gg < 16; ++gg) s += red[(oo * 16 + gg) * 17 + p];
            mu16[t] = s;
        }
        __syncthreads();
        // ---- sig ----
        #pragma unroll
        for (int p = 0; p < 16; ++p) ml[p] = mu16[o * 16 + p];
        {
            float invr = 1.f / (rs[o] + EPSV);
            float pm[16];
            #pragma unroll
            for (int p = 0; p < 16; ++p) pm[p] = 0.f;
            #pragma unroll
            for (int jj = 0; jj < 9; ++jj) {
                float c = rw_s[(jj * 16 + g) * 16 + o] * invr;
                #pragma unroll
                for (int p = 0; p < 16; ++p) { float d = v[jj][p] - ml[p]; pm[p] = fmaf(c * d, d, pm[p]); }
            }
            #pragma unroll
            for (int p = 0; p < 16; ++p) red[(o * 16 + g) * 17 + p] = pm[p];
        }
        __syncthreads();
        {
            int oo = t >> 4, p = t & 15; float s = 0.f;
            #pragma unroll
            for (int gg = 0; gg < 16; ++gg) s += red[(oo * 16 + gg) * 17 + p];
            s += EPSV;
            sig16[t] = s; lsig16[t] = logf(s);
        }
        __syncthreads();
        // ---- cost / a_out ----
        { int oo = t >> 4; ps[t] = (bu[oo] + 0.5f * lsig16[t]) * rs[oo]; }
        __syncthreads();
        if (t < 16) {
            float c = 0.f;
            #pragma unroll
            for (int p = 0; p < 16; ++p) c += ps[t * 16 + p];
            float ao = sigmoidf_(lam * (ba[t] - c));
            aout[t] = ao; laout[t] = logf(ao);
        }
        __syncthreads();
        // ---- E-step ----
        if (it < 2) {
            float isl[16]; float cst = -8.f * LN_2PI;
            #pragma unroll
            for (int p = 0; p < 16; ++p) { isl[p] = 1.f / sig16[o * 16 + p]; cst -= 0.5f * lsig16[o * 16 + p]; }
            #pragma unroll
            for (int jj = 0; jj < 9; ++jj) {
                float s = 0.f;
                #pragma unroll
                for (int p = 0; p < 16; ++p) { float d = v[jj][p] - ml[p]; s = fmaf(d * d, isl[p], s); }
                r_s[(jj * 16 + g) * 16 + o] = -0.5f * s + cst;
            }
            __syncthreads();
            if (t < 144) {
                float lv[16]; float mx = -1e30f;
                #pragma unroll
                for (int oo = 0; oo < 16; ++oo) { lv[oo] = r_s[t * 16 + oo] + laout[oo]; mx = fmaxf(mx, lv[oo]); }
                float den = 0.f;
                #pragma unroll
                for (int oo = 0; oo < 16; ++oo) { float e = expf(lv[oo] - mx); lv[oo] = e; den += e; }
                float inv = 1.f / den;
                #pragma unroll
                for (int oo = 0; oo < 16; ++oo) r_s[t * 16 + oo] = lv[oo] * inv;
            }
        }
    }
    __syncthreads();
    // ---- outputs: a_out and BN(pose=mu) ----
    {
        float sc = bng[t] * rsqrtf(bnv[t] + BN_EPS);
        pose_out[(bidx * 256 + t) * 64 + l] = (mu16[t] - bnm[t]) * sc + bnb[t];
        if (t < 16) a_out_g[(bidx * 16 + t) * 64 + l] = aout[t];
    }
}

// ---------------- EM routing, FC-type (k=4, pad=0), A=16, B=10, P=16 ----------------
// grid: 32*25 blocks; block 256 threads, thread = k (kkA = 256 exactly)
__global__ __launch_bounds__(256, 2) void k_em_fc(
    const float* __restrict__ a_in, const float* __restrict__ pose_in,
    const float* __restrict__ W, const float* __restrict__ bu, const float* __restrict__ ba,
    float* __restrict__ out)
{
    __shared__ float wsum[4 * 160];
    __shared__ float mu_s[160], sig_s[160], lsig_s[160], isig_s[160];
    __shared__ float rs_s[10], aout_s[10], laout_s[10], cst_s[10];
    __shared__ float cbuf[160];

    const int t = threadIdx.x;
    const int bidx = blockIdx.x / 25;
    const int l = blockIdx.x % 25;
    const int y = l / 5, xo = l % 5;
    const int a = t & 15, kk = t >> 4;
    const int iy = y + (kk >> 2), ix = xo + (kk & 3);
    const int lane = t & 63, wv = t >> 6;

    float pcl[16];
    #pragma unroll
    for (int p = 0; p < 16; ++p) pcl[p] = pose_in[(bidx * 256 + a * 16 + p) * 64 + iy * 8 + ix];
    const float av = a_in[(bidx * 16 + a) * 64 + iy * 8 + ix];

    float v[10][16];
    const float4* W4 = reinterpret_cast<const float4*>(W);
    #pragma unroll
    for (int oo = 0; oo < 10; ++oo) {
        float wk[16];
        #pragma unroll
        for (int c = 0; c < 4; ++c) {
            float4 w4 = W4[(t * 10 + oo) * 4 + c];
            wk[c * 4 + 0] = w4.x; wk[c * 4 + 1] = w4.y; wk[c * 4 + 2] = w4.z; wk[c * 4 + 3] = w4.w;
        }
        #pragma unroll
        for (int i = 0; i < 4; ++i)
            #pragma unroll
            for (int j = 0; j < 4; ++j) {
                float s = 0.f;
                #pragma unroll
                for (int h = 0; h < 4; ++h) s = fmaf(pcl[i * 4 + h], wk[h * 4 + j], s);
                v[oo][i * 4 + j] = s;
            }
    }

    float r[10];
    #pragma unroll
    for (int oo = 0; oo < 10; ++oo) r[oo] = 0.1f;

    for (int it = 0; it < 3; ++it) {
        float lam = (it == 0) ? 5.0e-4f : ((it == 1) ? 9.75e-4f : 1.42625e-3f);
        float rw[10]; float den = EPSV;
        #pragma unroll
        for (int oo = 0; oo < 10; ++oo) { rw[oo] = r[oo] * av; den += rw[oo]; }
        float invd = 1.f / den;
        #pragma unroll
        for (int oo = 0; oo < 10; ++oo) rw[oo] *= invd;
        // r_sum over all 256 threads
        #pragma unroll
        for (int oo = 0; oo < 10; ++oo) {
            float val = rw[oo];
            for (int off = 1; off < 64; off <<= 1) val += __shfl_xor(val, off, 64);
            if (lane == 0) wsum[wv * 160 + oo] = val;
        }
        __syncthreads();
        if (t < 10) rs_s[t] = wsum[t] + wsum[160 + t] + wsum[320 + t] + wsum[480 + t];
        __syncthreads();
        float coeff[10];
        #pragma unroll
        for (int oo = 0; oo < 10; ++oo) coeff[oo] = rw[oo] / (rs_s[oo] + EPSV);
        // mu
        #pragma unroll
        for (int oo = 0; oo < 10; ++oo)
            #pragma unroll
            for (int p = 0; p < 16; ++p) {
                float val = coeff[oo] * v[oo][p];
                for (int off = 1; off < 64; off <<= 1) val += __shfl_xor(val, off, 64);
                if (lane == 0) wsum[wv * 160 + oo * 16 + p] = val;
            }
        __syncthreads();
        if (t < 160) mu_s[t] = wsum[t] + wsum[160 + t] + wsum[320 + t] + wsum[480 + t];
        __syncthreads();
        // sig
        #pragma unroll
        for (int oo = 0; oo < 10; ++oo)
            #pragma unroll
            for (int p = 0; p < 16; ++p) {
                float d = v[oo][p] - mu_s[oo * 16 + p];
                float val = coeff[oo] * d * d;
                for (int off = 1; off < 64; off <<= 1) val += __shfl_xor(val, off, 64);
                if (lane == 0) wsum[wv * 160 + oo * 16 + p] = val;
            }
        __syncthreads();
        if (t < 160) {
            float s = wsum[t] + wsum[160 + t] + wsum[320 + t] + wsum[480 + t] + EPSV;
            sig_s[t] = s; lsig_s[t] = logf(s); isig_s[t] = 1.f / s;
        }
        __syncthreads();
        if (t < 160) { int oo = t / 16; cbuf[t] = (bu[oo] + 0.5f * lsig_s[t]) * rs_s[oo]; }
        __syncthreads();
        if (t < 10) {
            float c = 0.f, cs = -8.f * LN_2PI;
            #pragma unroll
            for (int p = 0; p < 16; ++p) { c += cbuf[t * 16 + p]; cs -= 0.5f * lsig_s[t * 16 + p]; }
            float ao = sigmoidf_(lam * (ba[t] - c));
            aout_s[t] = ao; laout_s[t] = logf(ao); cst_s[t] = cs;
        }
        __syncthreads();
        if (it < 2) {
            float mx = -1e30f; float lg[10];
            #pragma unroll
            for (int oo = 0; oo < 10; ++oo) {
                float s = 0.f;
                #pragma unroll
                for (int p = 0; p < 16; ++p) {
                    float d = v[oo][p] - mu_s[oo * 16 + p];
                    s = fmaf(d * d, isig_s[oo * 16 + p], s);
                }
                lg[oo] = -0.5f * s + cst_s[oo] + laout_s[oo];
                mx = fmaxf(mx, lg[oo]);
            }
            float dn = 0.f;
            #pragma unroll
            for (int oo = 0; oo < 10; ++oo) { float e = expf(lg[oo] - mx); r[oo] = e; dn += e; }
            float inv = 1.f / dn;
            #pragma unroll
            for (int oo = 0; oo < 10; ++oo) r[oo] *= inv;
            __syncthreads();
        }
    }
    if (t < 10) atomicAdd(&out[bidx * 10 + t], aout_s[t] * 0.04f);
}

extern "C" void kernel_launch(void* const* d_in, const int* in_sizes, int n_in,
                              void* d_out, int out_size, void* d_ws, size_t ws_size,
                              hipStream_t stream)
{
    const float* x           = (const float*)d_in[0];
    const float* conv_a_w    = (const float*)d_in[1];
    const float* conv_pose_w = (const float*)d_in[2];
    const float* bn_a_g = (const float*)d_in[3];
    const float* bn_a_b = (const float*)d_in[4];
    const float* bn_a_m = (const float*)d_in[5];
    const float* bn_a_v = (const float*)d_in[6];
    const float* bn_p_g = (const float*)d_in[7];
    const float* bn_p_b = (const float*)d_in[8];
    const float* bn_p_m = (const float*)d_in[9];
    const float* bn_p_v = (const float*)d_in[10];
    const float* em0_W  = (const float*)d_in[11];
    const float* em0_bu = (const float*)d_in[12];
    const float* em0_ba = (const float*)d_in[13];
    const float* bn0_g  = (const float*)d_in[14];
    const float* bn0_b  = (const float*)d_in[15];
    const float* bn0_m  = (const float*)d_in[16];
    const float* bn0_v  = (const float*)d_in[17];
    const float* em1_W  = (const float*)d_in[18];
    const float* em1_bu = (const float*)d_in[19];
    const float* em1_ba = (const float*)d_in[20];
    const float* bn1_g  = (const float*)d_in[21];
    const float* bn1_b  = (const float*)d_in[22];
    const float* bn1_m  = (const float*)d_in[23];
    const float* bn1_v  = (const float*)d_in[24];
    const float* fc_W   = (const float*)d_in[25];
    const float* fc_bu  = (const float*)d_in[26];
    const float* fc_ba  = (const float*)d_in[27];

    float* ws    = (float*)d_ws;
    float* a0    = ws;                  // 32*16*64    = 32768
    float* pose0 = a0 + 32768;          // 32*256*64   = 524288
    float* a1    = pose0 + 524288;
    float* pose1 = a1 + 32768;
    float* a2    = pose1 + 524288;
    float* pose2 = a2 + 32768;
    float* out   = (float*)d_out;

    hipMemsetAsync(d_out, 0, (size_t)out_size * sizeof(float), stream);
    k_conv_a<<<32, 256, 0, stream>>>(x, conv_a_w, bn_a_g, bn_a_b, bn_a_m, bn_a_v, a0);
    k_conv_pose<<<512, 256, 0, stream>>>(x, conv_pose_w, bn_p_g, bn_p_b, bn_p_m, bn_p_v, pose0);
    k_em_conv<<<2048, 256, 0, stream>>>(a0, pose0, em0_W, em0_bu, em0_ba,
                                        bn0_g, bn0_b, bn0_m, bn0_v, a1, pose1);
    k_em_conv<<<2048, 256, 0, stream>>>(a1, pose1, em1_W, em1_bu, em1_ba,
                                        bn1_g, bn1_b, bn1_m, bn1_v, a2, pose2);
    k_em_fc<<<800, 256, 0, stream>>>(a2, pose2, fc_W, fc_bu, fc_ba, out);
}

// Round 3
// 899.920 us; speedup vs baseline: 1.3949x; 1.3949x over previous
//
#include <hip/hip_runtime.h>

#define EPSV 1e-8f
#define BN_EPS 1e-5f
#define LN_2PI 1.8378770664093453f

__device__ __forceinline__ float sigmoidf_(float x) { return 1.0f / (1.0f + expf(-x)); }

// ---------------- conv_a: 256->16, 3x3 pad1, BN + sigmoid ----------------
__global__ __launch_bounds__(256) void k_conv_a(
    const float* __restrict__ x, const float* __restrict__ w,
    const float* __restrict__ g, const float* __restrict__ b_,
    const float* __restrict__ m, const float* __restrict__ v,
    float* __restrict__ out)
{
    __shared__ float xs[128 * 64];
    const int t = threadIdx.x;
    const int bidx = blockIdx.x;
    const int pix = t & 63, py = pix >> 3, px = pix & 7;
    const int ocb = t >> 6;  // 0..3
    float acc[4] = {0.f, 0.f, 0.f, 0.f};
    for (int ch = 0; ch < 2; ++ch) {
        __syncthreads();
        for (int i = t; i < 128 * 64; i += 256)
            xs[i] = x[bidx * 16384 + ch * 8192 + i];
        __syncthreads();
        for (int icl = 0; icl < 128; ++icl) {
            int ic = ch * 128 + icl;
            #pragma unroll
            for (int ky = 0; ky < 3; ++ky) {
                int iy = py + ky - 1;
                #pragma unroll
                for (int kx = 0; kx < 3; ++kx) {
                    int ix = px + kx - 1;
                    float xv = (iy >= 0 && iy < 8 && ix >= 0 && ix < 8) ? xs[icl * 64 + iy * 8 + ix] : 0.f;
                    #pragma unroll
                    for (int q = 0; q < 4; ++q) {
                        int oc = ocb + 4 * q;
                        acc[q] = fmaf(w[(oc * 256 + ic) * 9 + ky * 3 + kx], xv, acc[q]);
                    }
                }
            }
        }
    }
    #pragma unroll
    for (int q = 0; q < 4; ++q) {
        int oc = ocb + 4 * q;
        float sc = g[oc] * rsqrtf(v[oc] + BN_EPS);
        float y = (acc[q] - m[oc]) * sc + b_[oc];
        out[(bidx * 16 + oc) * 64 + pix] = sigmoidf_(y);
    }
}

// ---------------- conv_pose: 256->256, 3x3 pad1, BN ----------------
__global__ __launch_bounds__(256) void k_conv_pose(
    const float* __restrict__ x, const float* __restrict__ w,
    const float* __restrict__ g, const float* __restrict__ b_,
    const float* __restrict__ m, const float* __restrict__ v,
    float* __restrict__ out)
{
    __shared__ float xs[128 * 64];
    const int t = threadIdx.x;
    const int bidx = blockIdx.x >> 4;
    const int ocg = blockIdx.x & 15;
    const int pix = t & 63, py = pix >> 3, px = pix & 7;
    const int ocb = t >> 6;
    float acc[4] = {0.f, 0.f, 0.f, 0.f};
    for (int ch = 0; ch < 2; ++ch) {
        __syncthreads();
        for (int i = t; i < 128 * 64; i += 256)
            xs[i] = x[bidx * 16384 + ch * 8192 + i];
        __syncthreads();
        for (int icl = 0; icl < 128; ++icl) {
            int ic = ch * 128 + icl;
            #pragma unroll
            for (int ky = 0; ky < 3; ++ky) {
                int iy = py + ky - 1;
                #pragma unroll
                for (int kx = 0; kx < 3; ++kx) {
                    int ix = px + kx - 1;
                    float xv = (iy >= 0 && iy < 8 && ix >= 0 && ix < 8) ? xs[icl * 64 + iy * 8 + ix] : 0.f;
                    #pragma unroll
                    for (int q = 0; q < 4; ++q) {
                        int oc = ocg * 16 + ocb + 4 * q;
                        acc[q] = fmaf(w[(oc * 256 + ic) * 9 + ky * 3 + kx], xv, acc[q]);
                    }
                }
            }
        }
    }
    #pragma unroll
    for (int q = 0; q < 4; ++q) {
        int oc = ocg * 16 + ocb + 4 * q;
        float sc = g[oc] * rsqrtf(v[oc] + BN_EPS);
        out[(bidx * 256 + oc) * 64 + pix] = (acc[q] - m[oc]) * sc + b_[oc];
    }
}

// ---------------- EM routing, conv-type (k=3, pad=1), A=B=16, P=16 ----------------
__global__ __launch_bounds__(256, 2) void k_em_conv(
    const float* __restrict__ a_in, const float* __restrict__ pose_in,
    const float* __restrict__ W, const float* __restrict__ bu, const float* __restrict__ ba,
    const float* __restrict__ bng, const float* __restrict__ bnb,
    const float* __restrict__ bnm, const float* __restrict__ bnv,
    float* __restrict__ a_out_g, float* __restrict__ pose_out)
{
    __shared__ float pcT[16 * 144];       // transposed pose patches [p][k]
    __shared__ float ain[144];
    __shared__ float r_s[144 * 16];       // routing r[k][o] (reused for ln_p)
    __shared__ float rw_s[144 * 16];      // normalized r*a
    __shared__ float red[16 * 16 * 17];   // reduction scratch [o][g][p], padded
    __shared__ float mu16[256], sig16[256], lsig16[256];
    __shared__ float ps[256];
    __shared__ float rs[16], aout[16], laout[16];

    const int t = threadIdx.x;
    const int bidx = blockIdx.x >> 6;
    const int l = blockIdx.x & 63;
    const int y = l >> 3, xo = l & 7;
    const int o = t >> 4, g = t & 15;

    // ---- stage pose patches (transposed) + a patches; init r ----
    for (int idx = t; idx < 2304; idx += 256) {
        int p = idx / 144, k = idx - p * 144;
        int a = k & 15, kk = k >> 4;
        int iy = y + kk / 3 - 1, ix = xo + (kk % 3) - 1;
        float val = 0.f;
        if (iy >= 0 && iy < 8 && ix >= 0 && ix < 8)
            val = pose_in[(bidx * 256 + a * 16 + p) * 64 + iy * 8 + ix];
        pcT[p * 144 + k] = val;
        r_s[idx] = 1.0f / 16.0f;
    }
    if (t < 144) {
        int a = t & 15, kk = t >> 4;
        int iy = y + kk / 3 - 1, ix = xo + (kk % 3) - 1;
        ain[t] = (iy >= 0 && iy < 8 && ix >= 0 && ix < 8) ? a_in[(bidx * 16 + a) * 64 + iy * 8 + ix] : 0.f;
    }
    __syncthreads();

    // ---- votes (registers): v = pc @ W per (k,o) ----
    float v[9][16];
    const float4* W4 = reinterpret_cast<const float4*>(W);
    #pragma unroll
    for (int jj = 0; jj < 9; ++jj) {
        int k = jj * 16 + g;
        float pcl[16];
        #pragma unroll
        for (int p = 0; p < 16; ++p) pcl[p] = pcT[p * 144 + k];
        float wk[16];
        #pragma unroll
        for (int c = 0; c < 4; ++c) {
            float4 w4 = W4[(k * 16 + o) * 4 + c];
            wk[c * 4 + 0] = w4.x; wk[c * 4 + 1] = w4.y; wk[c * 4 + 2] = w4.z; wk[c * 4 + 3] = w4.w;
        }
        #pragma unroll
        for (int i = 0; i < 4; ++i)
            #pragma unroll
            for (int j = 0; j < 4; ++j) {
                float s = 0.f;
                #pragma unroll
                for (int h = 0; h < 4; ++h) s = fmaf(pcl[i * 4 + h], wk[h * 4 + j], s);
                v[jj][i * 4 + j] = s;
            }
    }

    float ml[16];
    for (int it = 0; it < 3; ++it) {
        float lam = (it == 0) ? 5.0e-4f : ((it == 1) ? 9.75e-4f : 1.42625e-3f);
        __syncthreads();
        // ---- M: rw = r*a normalized over o per k ----
        if (t < 144) {
            float tmp[16]; float den = EPSV;
            float av = ain[t];
            #pragma unroll
            for (int oo = 0; oo < 16; ++oo) { tmp[oo] = r_s[t * 16 + oo] * av; den += tmp[oo]; }
            float inv = 1.f / den;
            #pragma unroll
            for (int oo = 0; oo < 16; ++oo) rw_s[t * 16 + oo] = tmp[oo] * inv;
        }
        __syncthreads();
        // ---- r_sum over k ----
        {
            float s = 0.f;
            #pragma unroll
            for (int jj = 0; jj < 9; ++jj) s += rw_s[(jj * 16 + g) * 16 + o];
            ps[o * 16 + g] = s;
        }
        __syncthreads();
        if (t < 16) {
            float s = 0.f;
            #pragma unroll
            for (int gg = 0; gg < 16; ++gg) s += ps[t * 16 + gg];
            rs[t] = s;
        }
        __syncthreads();
        // ---- mu ----
        {
            float invr = 1.f / (rs[o] + EPSV);
            float pm[16];
            #pragma unroll
            for (int p = 0; p < 16; ++p) pm[p] = 0.f;
            #pragma unroll
            for (int jj = 0; jj < 9; ++jj) {
                float c = rw_s[(jj * 16 + g) * 16 + o] * invr;
                #pragma unroll
                for (int p = 0; p < 16; ++p) pm[p] = fmaf(c, v[jj][p], pm[p]);
            }
            #pragma unroll
            for (int p = 0; p < 16; ++p) red[(o * 16 + g) * 17 + p] = pm[p];
        }
        __syncthreads();
        {
            int oo = t >> 4, p = t & 15; float s = 0.f;
            #pragma unroll
            for (int gg = 0; gg < 16; ++gg) s += red[(oo * 16 + gg) * 17 + p];
            mu16[t] = s;
        }
        __syncthreads();
        // ---- sig ----
        #pragma unroll
        for (int p = 0; p < 16; ++p) ml[p] = mu16[o * 16 + p];
        {
            float invr = 1.f / (rs[o] + EPSV);
            float pm[16];
            #pragma unroll
            for (int p = 0; p < 16; ++p) pm[p] = 0.f;
            #pragma unroll
            for (int jj = 0; jj < 9; ++jj) {
                float c = rw_s[(jj * 16 + g) * 16 + o] * invr;
                #pragma unroll
                for (int p = 0; p < 16; ++p) { float d = v[jj][p] - ml[p]; pm[p] = fmaf(c * d, d, pm[p]); }
            }
            #pragma unroll
            for (int p = 0; p < 16; ++p) red[(o * 16 + g) * 17 + p] = pm[p];
        }
        __syncthreads();
        {
            int oo = t >> 4, p = t & 15; float s = 0.f;
            #pragma unroll
            for (int gg = 0; gg < 16; ++gg) s += red[(oo * 16 + gg) * 17 + p];
            s += EPSV;
            sig16[t] = s; lsig16[t] = logf(s);
        }
        __syncthreads();
        // ---- cost / a_out ----
        { int oo = t >> 4; ps[t] = (bu[oo] + 0.5f * lsig16[t]) * rs[oo]; }
        __syncthreads();
        if (t < 16) {
            float c = 0.f;
            #pragma unroll
            for (int p = 0; p < 16; ++p) c += ps[t * 16 + p];
            float ao = sigmoidf_(lam * (ba[t] - c));
            aout[t] = ao; laout[t] = logf(ao);
        }
        __syncthreads();
        // ---- E-step ----
        if (it < 2) {
            float isl[16]; float cst = -8.f * LN_2PI;
            #pragma unroll
            for (int p = 0; p < 16; ++p) { isl[p] = 1.f / sig16[o * 16 + p]; cst -= 0.5f * lsig16[o * 16 + p]; }
            #pragma unroll
            for (int jj = 0; jj < 9; ++jj) {
                float s = 0.f;
                #pragma unroll
                for (int p = 0; p < 16; ++p) { float d = v[jj][p] - ml[p]; s = fmaf(d * d, isl[p], s); }
                r_s[(jj * 16 + g) * 16 + o] = -0.5f * s + cst;
            }
            __syncthreads();
            if (t < 144) {
                float lv[16]; float mx = -1e30f;
                #pragma unroll
                for (int oo = 0; oo < 16; ++oo) { lv[oo] = r_s[t * 16 + oo] + laout[oo]; mx = fmaxf(mx, lv[oo]); }
                float den = 0.f;
                #pragma unroll
                for (int oo = 0; oo < 16; ++oo) { float e = expf(lv[oo] - mx); lv[oo] = e; den += e; }
                float inv = 1.f / den;
                #pragma unroll
                for (int oo = 0; oo < 16; ++oo) r_s[t * 16 + oo] = lv[oo] * inv;
            }
        }
    }
    __syncthreads();
    // ---- outputs: a_out and BN(pose=mu) ----
    {
        float sc = bng[t] * rsqrtf(bnv[t] + BN_EPS);
        pose_out[(bidx * 256 + t) * 64 + l] = (mu16[t] - bnm[t]) * sc + bnb[t];
        if (t < 16) a_out_g[(bidx * 16 + t) * 64 + l] = aout[t];
    }
}

// ---------------- EM routing, FC-type (k=4, pad=0), A=16, B=10, P=16 ----------------
// grid: 32*25 blocks; block 320 threads = (o in [0,10)) x (g in [0,32)).
// Thread holds votes v[jj][16] for k = jj*32+g, jj in [0,8), at its o.
__global__ __launch_bounds__(320, 2) void k_em_fc(
    const float* __restrict__ a_in, const float* __restrict__ pose_in,
    const float* __restrict__ W, const float* __restrict__ bu, const float* __restrict__ ba,
    float* __restrict__ out)
{
    __shared__ float pcs[5440];        // pcs[k*17+p] during votes; red[t*17+p] after
    __shared__ float rws[256 * 11];    // r / rw / logits matrix [k][o], pad 11
    __shared__ float ain_s[256];
    __shared__ float mu_s[160];
    __shared__ float lsig_s[160];
    __shared__ float isig_s[160];
    __shared__ float cbuf[160];
    __shared__ float rs_s[10], aout_s[10], laout_s[10];
    __shared__ float bu_s[10], ba_s[10];

    const int t = threadIdx.x;
    const int bidx = blockIdx.x / 25;
    const int l = blockIdx.x % 25;
    const int y = l / 5, xo = l % 5;
    const int o = t >> 5, g = t & 31;

    // ---- stage pose patches [k][p] and a patches ----
    for (int idx = t; idx < 4096; idx += 320) {
        int k = idx >> 4, p = idx & 15;
        int a = k & 15, kk = k >> 4;
        int iy = y + (kk >> 2), ix = xo + (kk & 3);
        pcs[k * 17 + p] = pose_in[((bidx * 256 + a * 16 + p) << 6) + iy * 8 + ix];
    }
    if (t < 256) {
        int a = t & 15, kk = t >> 4;
        int iy = y + (kk >> 2), ix = xo + (kk & 3);
        ain_s[t] = a_in[((bidx * 16 + a) << 6) + iy * 8 + ix];
    }
    if (t < 10) { bu_s[t] = bu[t]; ba_s[t] = ba[t]; }
    __syncthreads();

    // ---- votes ----
    float v[8][16];
    const float4* W4 = reinterpret_cast<const float4*>(W);
    #pragma unroll
    for (int jj = 0; jj < 8; ++jj) {
        int k = jj * 32 + g;
        float pcl[16];
        #pragma unroll
        for (int p = 0; p < 16; ++p) pcl[p] = pcs[k * 17 + p];
        float wk[16];
        #pragma unroll
        for (int c = 0; c < 4; ++c) {
            float4 w4 = W4[(k * 10 + o) * 4 + c];
            wk[c * 4 + 0] = w4.x; wk[c * 4 + 1] = w4.y; wk[c * 4 + 2] = w4.z; wk[c * 4 + 3] = w4.w;
        }
        #pragma unroll
        for (int i = 0; i < 4; ++i)
            #pragma unroll
            for (int j = 0; j < 4; ++j) {
                float s = 0.f;
                #pragma unroll
                for (int h = 0; h < 4; ++h) s = fmaf(pcl[i * 4 + h], wk[h * 4 + j], s);
                v[jj][i * 4 + j] = s;
            }
    }
    float* red = pcs;  // alias: pcs no longer needed after votes

    float ml[16];
    for (int it = 0; it < 3; ++it) {
        float lam = (it == 0) ? 5.0e-4f : ((it == 1) ? 9.75e-4f : 1.42625e-3f);
        __syncthreads();
        // ---- per-k: softmax over o (it>0) then rw = r*a normalized over o ----
        if (t < 256) {
            float rr[10];
            if (it > 0) {
                float mx = -1e30f;
                #pragma unroll
                for (int oo = 0; oo < 10; ++oo) { rr[oo] = rws[t * 11 + oo]; mx = fmaxf(mx, rr[oo]); }
                float den = 0.f;
                #pragma unroll
                for (int oo = 0; oo < 10; ++oo) { float e = expf(rr[oo] - mx); rr[oo] = e; den += e; }
                float inv = 1.f / den;
                #pragma unroll
                for (int oo = 0; oo < 10; ++oo) rr[oo] *= inv;
            } else {
                #pragma unroll
                for (int oo = 0; oo < 10; ++oo) rr[oo] = 0.1f;
            }
            float av = ain_s[t];
            float den = EPSV;
            #pragma unroll
            for (int oo = 0; oo < 10; ++oo) { rr[oo] *= av; den += rr[oo]; }
            float inv = 1.f / den;
            #pragma unroll
            for (int oo = 0; oo < 10; ++oo) rws[t * 11 + oo] = rr[oo] * inv;
        }
        __syncthreads();
        // ---- load rw for my 8 k's; rsum via width-32 shfl ----
        float rwl[8]; float prs = 0.f;
        #pragma unroll
        for (int jj = 0; jj < 8; ++jj) { rwl[jj] = rws[(jj * 32 + g) * 11 + o]; prs += rwl[jj]; }
        #pragma unroll
        for (int off = 16; off > 0; off >>= 1) prs += __shfl_xor(prs, off, 32);
        if (g == 0) rs_s[o] = prs;
        __syncthreads();
        // ---- mu: partial over jj, LDS stage-2 over g ----
        {
            float pm[16];
            #pragma unroll
            for (int p = 0; p < 16; ++p) pm[p] = 0.f;
            #pragma unroll
            for (int jj = 0; jj < 8; ++jj)
                #pragma unroll
                for (int p = 0; p < 16; ++p) pm[p] = fmaf(rwl[jj], v[jj][p], pm[p]);
            #pragma unroll
            for (int p = 0; p < 16; ++p) red[t * 17 + p] = pm[p];
        }
        __syncthreads();
        if (t < 160) {
            int oo = t >> 4, p = t & 15; float s = 0.f;
            #pragma unroll
            for (int gg = 0; gg < 32; ++gg) s += red[(oo * 32 + gg) * 17 + p];
            mu_s[t] = s / (rs_s[oo] + EPSV);
        }
        __syncthreads();
        #pragma unroll
        for (int p = 0; p < 16; ++p) ml[p] = mu_s[o * 16 + p];
        // ---- sig ----
        {
            float pq[16];
            #pragma unroll
            for (int p = 0; p < 16; ++p) pq[p] = 0.f;
            #pragma unroll
            for (int jj = 0; jj < 8; ++jj)
                #pragma unroll
                for (int p = 0; p < 16; ++p) { float d = v[jj][p] - ml[p]; pq[p] = fmaf(rwl[jj] * d, d, pq[p]); }
            #pragma unroll
            for (int p = 0; p < 16; ++p) red[t * 17 + p] = pq[p];
        }
        __syncthreads();
        if (t < 160) {
            int oo = t >> 4, p = t & 15; float s = 0.f;
            #pragma unroll
            for (int gg = 0; gg < 32; ++gg) s += red[(oo * 32 + gg) * 17 + p];
            s = s / (rs_s[oo] + EPSV) + EPSV;
            float ls = logf(s);
            lsig_s[t] = ls; isig_s[t] = 1.f / s;
            cbuf[t] = (bu_s[oo] + 0.5f * ls) * rs_s[oo];
        }
        __syncthreads();
        if (t < 10) {
            float c = 0.f;
            #pragma unroll
            for (int p = 0; p < 16; ++p) c += cbuf[t * 16 + p];
            float ao = sigmoidf_(lam * (ba_s[t] - c));
            aout_s[t] = ao; laout_s[t] = logf(ao);
        }
        __syncthreads();
        // ---- E-step: write logits into rws[k][o] ----
        if (it < 2) {
            float isl[16]; float cst = -8.f * LN_2PI;
            #pragma unroll
            for (int p = 0; p < 16; ++p) { isl[p] = isig_s[o * 16 + p]; cst -= 0.5f * lsig_s[o * 16 + p]; }
            const float la = laout_s[o];
            #pragma unroll
            for (int jj = 0; jj < 8; ++jj) {
                float s = 0.f;
                #pragma unroll
                for (int p = 0; p < 16; ++p) { float d = v[jj][p] - ml[p]; s = fmaf(d * d, isl[p], s); }
                rws[(jj * 32 + g) * 11 + o] = -0.5f * s + cst + la;
            }
        }
    }
    if (t < 10) atomicAdd(&out[bidx * 10 + t], aout_s[t] * 0.04f);
}

extern "C" void kernel_launch(void* const* d_in, const int* in_sizes, int n_in,
                              void* d_out, int out_size, void* d_ws, size_t ws_size,
                              hipStream_t stream)
{
    const float* x           = (const float*)d_in[0];
    const float* conv_a_w    = (const float*)d_in[1];
    const float* conv_pose_w = (const float*)d_in[2];
    const float* bn_a_g = (const float*)d_in[3];
    const float* bn_a_b = (const float*)d_in[4];
    const float* bn_a_m = (const float*)d_in[5];
    const float* bn_a_v = (const float*)d_in[6];
    const float* bn_p_g = (const float*)d_in[7];
    const float* bn_p_b = (const float*)d_in[8];
    const float* bn_p_m = (const float*)d_in[9];
    const float* bn_p_v = (const float*)d_in[10];
    const float* em0_W  = (const float*)d_in[11];
    const float* em0_bu = (const float*)d_in[12];
    const float* em0_ba = (const float*)d_in[13];
    const float* bn0_g  = (const float*)d_in[14];
    const float* bn0_b  = (const float*)d_in[15];
    const float* bn0_m  = (const float*)d_in[16];
    const float* bn0_v  = (const float*)d_in[17];
    const float* em1_W  = (const float*)d_in[18];
    const float* em1_bu = (const float*)d_in[19];
    const float* em1_ba = (const float*)d_in[20];
    const float* bn1_g  = (const float*)d_in[21];
    const float* bn1_b  = (const float*)d_in[22];
    const float* bn1_m  = (const float*)d_in[23];
    const float* bn1_v  = (const float*)d_in[24];
    const float* fc_W   = (const float*)d_in[25];
    const float* fc_bu  = (const float*)d_in[26];
    const float* fc_ba  = (const float*)d_in[27];

    float* ws    = (float*)d_ws;
    float* a0    = ws;                  // 32*16*64    = 32768
    float* pose0 = a0 + 32768;          // 32*256*64   = 524288
    float* a1    = pose0 + 524288;
    float* pose1 = a1 + 32768;
    float* a2    = pose1 + 524288;
    float* pose2 = a2 + 32768;
    float* out   = (float*)d_out;

    hipMemsetAsync(d_out, 0, (size_t)out_size * sizeof(float), stream);
    k_conv_a<<<32, 256, 0, stream>>>(x, conv_a_w, bn_a_g, bn_a_b, bn_a_m, bn_a_v, a0);
    k_conv_pose<<<512, 256, 0, stream>>>(x, conv_pose_w, bn_p_g, bn_p_b, bn_p_m, bn_p_v, pose0);
    k_em_conv<<<2048, 256, 0, stream>>>(a0, pose0, em0_W, em0_bu, em0_ba,
                                        bn0_g, bn0_b, bn0_m, bn0_v, a1, pose1);
    k_em_conv<<<2048, 256, 0, stream>>>(a1, pose1, em1_W, em1_bu, em1_ba,
                                        bn1_g, bn1_b, bn1_m, bn1_v, a2, pose2);
    k_em_fc<<<800, 320, 0, stream>>>(a2, pose2, fc_W, fc_bu, fc_ba, out);
}

// Round 4
// 755.998 us; speedup vs baseline: 1.6604x; 1.1904x over previous
//
#include <hip/hip_runtime.h>

#define EPSV 1e-8f
#define BN_EPS 1e-5f
#define LN_2PI 1.8378770664093453f

__device__ __forceinline__ float sigmoidf_(float x) { return 1.0f / (1.0f + expf(-x)); }

// ---------------- generic 3x3 pad1 conv on 8x8, split-K over ic chunks ----------------
// grid = 32b x nOcg x nIcq ; block 256 = 64 pix x 4 ocb. Each thread: 4 oc (ocb+4q).
// Stages icChunk x 10x10 haloed tile (zeros in halo) -> no bounds checks in inner loop.
// Epilogue: atomicAdd(out, acc*sc) with BN affine folded; icq==0 adds the constant term.
__global__ __launch_bounds__(256) void k_conv3(
    const float* __restrict__ x, const float* __restrict__ w,
    const float* __restrict__ g, const float* __restrict__ b_,
    const float* __restrict__ m, const float* __restrict__ v,
    float* __restrict__ out, int OC, int nOcg, int nIcq, int icChunk)
{
    __shared__ float xs[6400];  // up to 64 ic x 100 (10x10 halo)
    const int t = threadIdx.x;
    const int per_b = nOcg * nIcq;
    const int bidx = blockIdx.x / per_b;
    const int rem = blockIdx.x - bidx * per_b;
    const int ocg = rem / nIcq;
    const int icq = rem - ocg * nIcq;
    const int pix = t & 63, py = pix >> 3, px = pix & 7;
    const int ocb = t >> 6;
    const int ic0 = icq * icChunk;

    const int cells = icChunk * 100;
    for (int idx = t; idx < cells; idx += 256) {
        int icl = idx / 100;
        int c = idx - icl * 100;
        int iy = c / 10, ix = c - iy * 10;
        float val = 0.f;
        if (iy >= 1 && iy <= 8 && ix >= 1 && ix <= 8)
            val = x[(bidx * 256 + ic0 + icl) * 64 + (iy - 1) * 8 + (ix - 1)];
        xs[idx] = val;
    }
    __syncthreads();

    float acc[4] = {0.f, 0.f, 0.f, 0.f};
    for (int icl = 0; icl < icChunk; ++icl) {
        const float* wp = &w[((ocg * 16 + ocb) * 256 + ic0 + icl) * 9];
        const float* xr = &xs[icl * 100 + py * 10 + px];
        #pragma unroll
        for (int ky = 0; ky < 3; ++ky)
            #pragma unroll
            for (int kx = 0; kx < 3; ++kx) {
                float xv = xr[ky * 10 + kx];
                #pragma unroll
                for (int q = 0; q < 4; ++q)
                    acc[q] = fmaf(wp[q * 9216 + ky * 3 + kx], xv, acc[q]);  // 4*256*9 = 9216
            }
    }
    #pragma unroll
    for (int q = 0; q < 4; ++q) {
        int oc = ocg * 16 + ocb + 4 * q;
        float sc = g[oc] * rsqrtf(v[oc] + BN_EPS);
        float add = acc[q] * sc;
        if (icq == 0) add += b_[oc] - m[oc] * sc;
        atomicAdd(&out[(bidx * OC + oc) * 64 + pix], add);
    }
}

// sigmoid epilogue for conv_a output
__global__ void k_sig(float* __restrict__ a, int n)
{
    int i = blockIdx.x * 256 + threadIdx.x;
    if (i < n) a[i] = 1.f / (1.f + expf(-a[i]));
}

// ---------------- EM routing, conv-type (k=3, pad=1), A=B=16, P=16 ----------------
// grid: 32*64 blocks (b,l); block 768 threads = (jt in 3) x (o in 16) x (g in 16).
// Thread holds votes v[jx][16] for k = (jt*3+jx)*16 + g, at its o. No spill (48 regs for v).
// Reductions over k: 3-term serial (jx) + 2-level shfl over g&3 + LDS stage-2 over 12 partials.
// mu/sig fused in one moment pass: sig = E2 - mu^2*(2-beta), beta = rs/(rs+eps).
__global__ __launch_bounds__(768, 3) void k_em_conv(
    const float* __restrict__ a_in, const float* __restrict__ pose_in,
    const float* __restrict__ W, const float* __restrict__ bu, const float* __restrict__ ba,
    const float* __restrict__ bng, const float* __restrict__ bnb,
    const float* __restrict__ bnm, const float* __restrict__ bnv,
    float* __restrict__ a_out_g, float* __restrict__ pose_out)
{
    __shared__ float uni[6528] __attribute__((aligned(16)));  // pc_s[2880] (votes) / red_pm[3264]+red_pq[3264] (iters)
    __shared__ float r_s[2448];       // logits/routing [k][17] (pad col unused)
    __shared__ float rw_s[2448];      // normalized r*a [k][17]
    __shared__ float prsum[192];      // rsum partials [u=jt*4+gh][16 o]
    __shared__ float a_s[144];
    __shared__ float mu_s[272], lsig_s[272], isig_s[272];  // [o*17 + p]
    __shared__ float cbuf[256];
    __shared__ float aout_s[16], laout_s[16];

    const int t = threadIdx.x;
    const int bidx = blockIdx.x >> 6;
    const int l = blockIdx.x & 63;
    const int y = l >> 3, xo = l & 7;
    const int jt = t >> 8;            // 0..2
    const int o = (t >> 4) & 15;
    const int g = t & 15;
    const int gh = g >> 2;

    float* pc_s = uni;                // [k*20 + p]
    float* red_pm = uni;              // [((jt*4+gh)*16+o)*17 + p]
    float* red_pq = uni + 3264;

    // ---- stage pose patches, a patches; zero-init routing logits ----
    for (int idx = t; idx < 2304; idx += 768) {
        int k = idx >> 4, p = idx & 15;
        int a = k & 15, kk = k >> 4;
        int iy = y + kk / 3 - 1, ix = xo + (kk % 3) - 1;
        float val = 0.f;
        if (iy >= 0 && iy < 8 && ix >= 0 && ix < 8)
            val = pose_in[(bidx * 256 + a * 16 + p) * 64 + iy * 8 + ix];
        pc_s[k * 20 + p] = val;
    }
    for (int idx = t; idx < 2448; idx += 768) r_s[idx] = 0.f;
    if (t < 144) {
        int a = t & 15, kk = t >> 4;
        int iy = y + kk / 3 - 1, ix = xo + (kk % 3) - 1;
        a_s[t] = (iy >= 0 && iy < 8 && ix >= 0 && ix < 8) ? a_in[(bidx * 16 + a) * 64 + iy * 8 + ix] : 0.f;
    }
    __syncthreads();

    // ---- votes: 3 per thread ----
    float v[3][16];
    const float4* W4 = reinterpret_cast<const float4*>(W);
    #pragma unroll
    for (int jx = 0; jx < 3; ++jx) {
        int k = (jt * 3 + jx) * 16 + g;
        float pcl[16];
        #pragma unroll
        for (int c = 0; c < 4; ++c) {
            float4 p4 = *reinterpret_cast<const float4*>(&pc_s[k * 20 + c * 4]);
            pcl[c * 4 + 0] = p4.x; pcl[c * 4 + 1] = p4.y; pcl[c * 4 + 2] = p4.z; pcl[c * 4 + 3] = p4.w;
        }
        float wk[16];
        #pragma unroll
        for (int c = 0; c < 4; ++c) {
            float4 w4 = W4[(k * 16 + o) * 4 + c];
            wk[c * 4 + 0] = w4.x; wk[c * 4 + 1] = w4.y; wk[c * 4 + 2] = w4.z; wk[c * 4 + 3] = w4.w;
        }
        #pragma unroll
        for (int i = 0; i < 4; ++i)
            #pragma unroll
            for (int j = 0; j < 4; ++j) {
                float s = 0.f;
                #pragma unroll
                for (int h = 0; h < 4; ++h) s = fmaf(pcl[i * 4 + h], wk[h * 4 + j], s);
                v[jx][i * 4 + j] = s;
            }
    }
    __syncthreads();  // pc_s dead; red region live below

    for (int it = 0; it < 3; ++it) {
        float lam = (it == 0) ? 5.0e-4f : ((it == 1) ? 9.75e-4f : 1.42625e-3f);
        // ---- B: per-k softmax over o, then rw = r*a / (sum_o + eps) ----
        if (t < 144) {
            float lv[16]; float mx = -1e30f;
            #pragma unroll
            for (int oo = 0; oo < 16; ++oo) { lv[oo] = r_s[t * 17 + oo]; mx = fmaxf(mx, lv[oo]); }
            float den = 0.f;
            #pragma unroll
            for (int oo = 0; oo < 16; ++oo) { float e = expf(lv[oo] - mx); lv[oo] = e; den += e; }
            float inv = 1.f / den;
            float av = a_s[t];
            float den2 = EPSV;
            #pragma unroll
            for (int oo = 0; oo < 16; ++oo) { float tmp = lv[oo] * inv * av; lv[oo] = tmp; den2 += tmp; }
            float i2 = 1.f / den2;
            #pragma unroll
            for (int oo = 0; oo < 16; ++oo) rw_s[t * 17 + oo] = lv[oo] * i2;
        }
        __syncthreads();
        // ---- C: moment pass (rsum, sum rw*v, sum rw*v^2), reduce over g ----
        {
            float rwl[3];
            #pragma unroll
            for (int jx = 0; jx < 3; ++jx) rwl[jx] = rw_s[((jt * 3 + jx) * 16 + g) * 17 + o];
            float prw = rwl[0] + rwl[1] + rwl[2];
            float pm[16], pq[16];
            #pragma unroll
            for (int p = 0; p < 16; ++p) { pm[p] = 0.f; pq[p] = 0.f; }
            #pragma unroll
            for (int jx = 0; jx < 3; ++jx) {
                float r = rwl[jx];
                #pragma unroll
                for (int p = 0; p < 16; ++p) {
                    float vv = v[jx][p];
                    pm[p] = fmaf(r, vv, pm[p]);
                    pq[p] = fmaf(r * vv, vv, pq[p]);
                }
            }
            prw += __shfl_xor(prw, 1, 64); prw += __shfl_xor(prw, 2, 64);
            #pragma unroll
            for (int p = 0; p < 16; ++p) {
                pm[p] += __shfl_xor(pm[p], 1, 64); pm[p] += __shfl_xor(pm[p], 2, 64);
                pq[p] += __shfl_xor(pq[p], 1, 64); pq[p] += __shfl_xor(pq[p], 2, 64);
            }
            if ((g & 3) == 0) {
                int u = jt * 4 + gh;
                int row = (u * 16 + o) * 17;
                prsum[u * 16 + o] = prw;
                #pragma unroll
                for (int p = 0; p < 16; ++p) { red_pm[row + p] = pm[p]; red_pq[row + p] = pq[p]; }
            }
        }
        __syncthreads();
        // ---- D: stage-2 (12 partials) -> mu, sig, lsig, isig, cost terms ----
        if (t < 256) {
            int oo = t >> 4, p = t & 15;
            float spm = 0.f, spq = 0.f, srs = 0.f;
            #pragma unroll
            for (int u = 0; u < 12; ++u) {
                int row = (u * 16 + oo) * 17;
                spm += red_pm[row + p];
                spq += red_pq[row + p];
                srs += prsum[u * 16 + oo];
            }
            float invr = 1.f / (srs + EPSV);
            float mu = spm * invr;
            float beta = srs * invr;
            float E2 = spq * invr;
            float sig = fmaf(-(2.f - beta) * mu, mu, E2) + EPSV;
            float ls = logf(sig);
            mu_s[oo * 17 + p] = mu;
            lsig_s[oo * 17 + p] = ls;
            isig_s[oo * 17 + p] = 1.f / sig;
            cbuf[t] = (bu[oo] + 0.5f * ls) * srs;
        }
        __syncthreads();
        // ---- E: a_out ----
        if (t < 16) {
            float c = 0.f;
            #pragma unroll
            for (int p = 0; p < 16; ++p) c += cbuf[t * 16 + p];
            float ao = sigmoidf_(lam * (ba[t] - c));
            aout_s[t] = ao; laout_s[t] = logf(ao);
        }
        __syncthreads();
        // ---- F: E-step logits -> r_s ----
        if (it < 2) {
            float s0 = 0.f, s1 = 0.f, s2 = 0.f;
            float cst = -8.f * LN_2PI;
            const float la = laout_s[o];
            #pragma unroll
            for (int p = 0; p < 16; ++p) {
                float ml = mu_s[o * 17 + p];
                float isg = isig_s[o * 17 + p];
                cst -= 0.5f * lsig_s[o * 17 + p];
                float d0 = v[0][p] - ml; s0 = fmaf(d0 * d0, isg, s0);
                float d1 = v[1][p] - ml; s1 = fmaf(d1 * d1, isg, s1);
                float d2 = v[2][p] - ml; s2 = fmaf(d2 * d2, isg, s2);
            }
            r_s[((jt * 3 + 0) * 16 + g) * 17 + o] = fmaf(-0.5f, s0, cst) + la;
            r_s[((jt * 3 + 1) * 16 + g) * 17 + o] = fmaf(-0.5f, s1, cst) + la;
            r_s[((jt * 3 + 2) * 16 + g) * 17 + o] = fmaf(-0.5f, s2, cst) + la;
        }
        __syncthreads();
    }
    // ---- outputs: BN(pose=mu) and a_out ----
    if (t < 256) {
        float sc = bng[t] * rsqrtf(bnv[t] + BN_EPS);
        float mu = mu_s[(t >> 4) * 17 + (t & 15)];
        pose_out[(bidx * 256 + t) * 64 + l] = (mu - bnm[t]) * sc + bnb[t];
    }
    if (t < 16) a_out_g[(bidx * 16 + t) * 64 + l] = aout_s[t];
}

// ---------------- EM routing, FC-type (k=4, pad=0), A=16, B=10, P=16 ----------------
// grid: 32*25 blocks; block 320 threads = (o in [0,10)) x (g in [0,32)).
__global__ __launch_bounds__(320, 2) void k_em_fc(
    const float* __restrict__ a_in, const float* __restrict__ pose_in,
    const float* __restrict__ W, const float* __restrict__ bu, const float* __restrict__ ba,
    float* __restrict__ out)
{
    __shared__ float pcs[5440];        // pcs[k*17+p] during votes; red[t*17+p] after
    __shared__ float rws[256 * 11];    // r / rw / logits matrix [k][o], pad 11
    __shared__ float ain_s[256];
    __shared__ float mu_s[160];
    __shared__ float lsig_s[160];
    __shared__ float isig_s[160];
    __shared__ float cbuf[160];
    __shared__ float rs_s[10], aout_s[10], laout_s[10];
    __shared__ float bu_s[10], ba_s[10];

    const int t = threadIdx.x;
    const int bidx = blockIdx.x / 25;
    const int l = blockIdx.x % 25;
    const int y = l / 5, xo = l % 5;
    const int o = t >> 5, g = t & 31;

    for (int idx = t; idx < 4096; idx += 320) {
        int k = idx >> 4, p = idx & 15;
        int a = k & 15, kk = k >> 4;
        int iy = y + (kk >> 2), ix = xo + (kk & 3);
        pcs[k * 17 + p] = pose_in[((bidx * 256 + a * 16 + p) << 6) + iy * 8 + ix];
    }
    if (t < 256) {
        int a = t & 15, kk = t >> 4;
        int iy = y + (kk >> 2), ix = xo + (kk & 3);
        ain_s[t] = a_in[((bidx * 16 + a) << 6) + iy * 8 + ix];
    }
    if (t < 10) { bu_s[t] = bu[t]; ba_s[t] = ba[t]; }
    __syncthreads();

    float v[8][16];
    const float4* W4 = reinterpret_cast<const float4*>(W);
    #pragma unroll
    for (int jj = 0; jj < 8; ++jj) {
        int k = jj * 32 + g;
        float pcl[16];
        #pragma unroll
        for (int p = 0; p < 16; ++p) pcl[p] = pcs[k * 17 + p];
        float wk[16];
        #pragma unroll
        for (int c = 0; c < 4; ++c) {
            float4 w4 = W4[(k * 10 + o) * 4 + c];
            wk[c * 4 + 0] = w4.x; wk[c * 4 + 1] = w4.y; wk[c * 4 + 2] = w4.z; wk[c * 4 + 3] = w4.w;
        }
        #pragma unroll
        for (int i = 0; i < 4; ++i)
            #pragma unroll
            for (int j = 0; j < 4; ++j) {
                float s = 0.f;
                #pragma unroll
                for (int h = 0; h < 4; ++h) s = fmaf(pcl[i * 4 + h], wk[h * 4 + j], s);
                v[jj][i * 4 + j] = s;
            }
    }
    float* red = pcs;

    float ml[16];
    for (int it = 0; it < 3; ++it) {
        float lam = (it == 0) ? 5.0e-4f : ((it == 1) ? 9.75e-4f : 1.42625e-3f);
        __syncthreads();
        if (t < 256) {
            float rr[10];
            if (it > 0) {
                float mx = -1e30f;
                #pragma unroll
                for (int oo = 0; oo < 10; ++oo) { rr[oo] = rws[t * 11 + oo]; mx = fmaxf(mx, rr[oo]); }
                float den = 0.f;
                #pragma unroll
                for (int oo = 0; oo < 10; ++oo) { float e = expf(rr[oo] - mx); rr[oo] = e; den += e; }
                float inv = 1.f / den;
                #pragma unroll
                for (int oo = 0; oo < 10; ++oo) rr[oo] *= inv;
            } else {
                #pragma unroll
                for (int oo = 0; oo < 10; ++oo) rr[oo] = 0.1f;
            }
            float av = ain_s[t];
            float den = EPSV;
            #pragma unroll
            for (int oo = 0; oo < 10; ++oo) { rr[oo] *= av; den += rr[oo]; }
            float inv = 1.f / den;
            #pragma unroll
            for (int oo = 0; oo < 10; ++oo) rws[t * 11 + oo] = rr[oo] * inv;
        }
        __syncthreads();
        float rwl[8]; float prs = 0.f;
        #pragma unroll
        for (int jj = 0; jj < 8; ++jj) { rwl[jj] = rws[(jj * 32 + g) * 11 + o]; prs += rwl[jj]; }
        #pragma unroll
        for (int off = 16; off > 0; off >>= 1) prs += __shfl_xor(prs, off, 32);
        if (g == 0) rs_s[o] = prs;
        __syncthreads();
        {
            float pm[16];
            #pragma unroll
            for (int p = 0; p < 16; ++p) pm[p] = 0.f;
            #pragma unroll
            for (int jj = 0; jj < 8; ++jj)
                #pragma unroll
                for (int p = 0; p < 16; ++p) pm[p] = fmaf(rwl[jj], v[jj][p], pm[p]);
            #pragma unroll
            for (int p = 0; p < 16; ++p) red[t * 17 + p] = pm[p];
        }
        __syncthreads();
        if (t < 160) {
            int oo = t >> 4, p = t & 15; float s = 0.f;
            #pragma unroll
            for (int gg = 0; gg < 32; ++gg) s += red[(oo * 32 + gg) * 17 + p];
            mu_s[t] = s / (rs_s[oo] + EPSV);
        }
        __syncthreads();
        #pragma unroll
        for (int p = 0; p < 16; ++p) ml[p] = mu_s[o * 16 + p];
        {
            float pq[16];
            #pragma unroll
            for (int p = 0; p < 16; ++p) pq[p] = 0.f;
            #pragma unroll
            for (int jj = 0; jj < 8; ++jj)
                #pragma unroll
                for (int p = 0; p < 16; ++p) { float d = v[jj][p] - ml[p]; pq[p] = fmaf(rwl[jj] * d, d, pq[p]); }
            #pragma unroll
            for (int p = 0; p < 16; ++p) red[t * 17 + p] = pq[p];
        }
        __syncthreads();
        if (t < 160) {
            int oo = t >> 4, p = t & 15; float s = 0.f;
            #pragma unroll
            for (int gg = 0; gg < 32; ++gg) s += red[(oo * 32 + gg) * 17 + p];
            s = s / (rs_s[oo] + EPSV) + EPSV;
            float ls = logf(s);
            lsig_s[t] = ls; isig_s[t] = 1.f / s;
            cbuf[t] = (bu_s[oo] + 0.5f * ls) * rs_s[oo];
        }
        __syncthreads();
        if (t < 10) {
            float c = 0.f;
            #pragma unroll
            for (int p = 0; p < 16; ++p) c += cbuf[t * 16 + p];
            float ao = sigmoidf_(lam * (ba_s[t] - c));
            aout_s[t] = ao; laout_s[t] = logf(ao);
        }
        __syncthreads();
        if (it < 2) {
            float isl[16]; float cst = -8.f * LN_2PI;
            #pragma unroll
            for (int p = 0; p < 16; ++p) { isl[p] = isig_s[o * 16 + p]; cst -= 0.5f * lsig_s[o * 16 + p]; }
            const float la = laout_s[o];
            #pragma unroll
            for (int jj = 0; jj < 8; ++jj) {
                float s = 0.f;
                #pragma unroll
                for (int p = 0; p < 16; ++p) { float d = v[jj][p] - ml[p]; s = fmaf(d * d, isl[p], s); }
                rws[(jj * 32 + g) * 11 + o] = -0.5f * s + cst + la;
            }
        }
    }
    if (t < 10) atomicAdd(&out[bidx * 10 + t], aout_s[t] * 0.04f);
}

extern "C" void kernel_launch(void* const* d_in, const int* in_sizes, int n_in,
                              void* d_out, int out_size, void* d_ws, size_t ws_size,
                              hipStream_t stream)
{
    const float* x           = (const float*)d_in[0];
    const float* conv_a_w    = (const float*)d_in[1];
    const float* conv_pose_w = (const float*)d_in[2];
    const float* bn_a_g = (const float*)d_in[3];
    const float* bn_a_b = (const float*)d_in[4];
    const float* bn_a_m = (const float*)d_in[5];
    const float* bn_a_v = (const float*)d_in[6];
    const float* bn_p_g = (const float*)d_in[7];
    const float* bn_p_b = (const float*)d_in[8];
    const float* bn_p_m = (const float*)d_in[9];
    const float* bn_p_v = (const float*)d_in[10];
    const float* em0_W  = (const float*)d_in[11];
    const float* em0_bu = (const float*)d_in[12];
    const float* em0_ba = (const float*)d_in[13];
    const float* bn0_g  = (const float*)d_in[14];
    const float* bn0_b  = (const float*)d_in[15];
    const float* bn0_m  = (const float*)d_in[16];
    const float* bn0_v  = (const float*)d_in[17];
    const float* em1_W  = (const float*)d_in[18];
    const float* em1_bu = (const float*)d_in[19];
    const float* em1_ba = (const float*)d_in[20];
    const float* bn1_g  = (const float*)d_in[21];
    const float* bn1_b  = (const float*)d_in[22];
    const float* bn1_m  = (const float*)d_in[23];
    const float* bn1_v  = (const float*)d_in[24];
    const float* fc_W   = (const float*)d_in[25];
    const float* fc_bu  = (const float*)d_in[26];
    const float* fc_ba  = (const float*)d_in[27];

    float* ws    = (float*)d_ws;
    float* a0    = ws;                  // 32*16*64    = 32768
    float* pose0 = a0 + 32768;          // 32*256*64   = 524288
    float* a1    = pose0 + 524288;
    float* pose1 = a1 + 32768;
    float* a2    = pose1 + 524288;
    float* pose2 = a2 + 32768;
    float* out   = (float*)d_out;

    hipMemsetAsync(d_out, 0, (size_t)out_size * sizeof(float), stream);
    hipMemsetAsync(a0, 0, (size_t)(32768 + 524288) * sizeof(float), stream);  // a0 + pose0 (atomic targets)
    // conv_a: OC=16, 1 ocg, 8 ic-chunks of 32 -> 256 blocks
    k_conv3<<<256, 256, 0, stream>>>(x, conv_a_w, bn_a_g, bn_a_b, bn_a_m, bn_a_v,
                                     a0, 16, 1, 8, 32);
    // conv_pose: OC=256, 16 ocg, 4 ic-chunks of 64 -> 2048 blocks
    k_conv3<<<2048, 256, 0, stream>>>(x, conv_pose_w, bn_p_g, bn_p_b, bn_p_m, bn_p_v,
                                      pose0, 256, 16, 4, 64);
    k_sig<<<128, 256, 0, stream>>>(a0, 32768);
    k_em_conv<<<2048, 768, 0, stream>>>(a0, pose0, em0_W, em0_bu, em0_ba,
                                        bn0_g, bn0_b, bn0_m, bn0_v, a1, pose1);
    k_em_conv<<<2048, 768, 0, stream>>>(a1, pose1, em1_W, em1_bu, em1_ba,
                                        bn1_g, bn1_b, bn1_m, bn1_v, a2, pose2);
    k_em_fc<<<800, 320, 0, stream>>>(a2, pose2, fc_W, fc_bu, fc_ba, out);
}